// Round 1
// baseline (733.735 us; speedup 1.0000x reference)
//
#include <hip/hip_runtime.h>
#include <math.h>

constexpr int Bc = 2, Hc = 16, Cc = 4, PXc = 16, PYc = 16, EXTRAc = 64, HDc = 64;
constexpr int Nc = Cc * PXc * PYc + EXTRAc;   // 1088
constexpr int TK = 16;                         // keys per LDS tile
constexpr int NKT = Nc / TK;                   // 68
constexpr int QROWS = 128;
constexpr int NQT = (Nc + QROWS - 1) / QROWS;  // 9
constexpr int LDSTR = 68;                      // padded LDS row stride (floats)
constexpr int BDIM = 128;

// ws layout (floats): [0..383]  mats: [b][c][which][16], which: 0=P(Mo), 1=P^T(Mq), 2=P_inv(Mkv)
//                     [384.. ]  trig: [n][32] = cosx[8], sinx[8], cosy[8], siny[8]

__global__ void prope_precompute_kernel(const float* __restrict__ viewmats,
                                        const float* __restrict__ Ks,
                                        float* __restrict__ ws) {
    int t = blockIdx.x * blockDim.x + threadIdx.x;
    if (t < Nc) {
        float* trig = ws + 384 + t * 32;
        if (t < EXTRAc) {
            #pragma unroll
            for (int f = 0; f < 8; ++f) {
                trig[f] = 1.f; trig[8 + f] = 0.f; trig[16 + f] = 1.f; trig[24 + f] = 0.f;
            }
        } else {
            int sidx = t - EXTRAc;
            float px = (float)(sidx & (PXc - 1));
            float py = (float)((sidx >> 4) & (PYc - 1));
            #pragma unroll
            for (int f = 0; f < 8; ++f) {
                float freq = powf(100.0f, -(float)f * 0.125f);
                float ax = px * freq, ay = py * freq;
                trig[f]      = cosf(ax);
                trig[8 + f]  = sinf(ax);
                trig[16 + f] = cosf(ay);
                trig[24 + f] = sinf(ay);
            }
        }
    }
    if (t < Bc * Cc) {
        int b = t / Cc, c = t % Cc;
        const float* V  = viewmats + (b * Cc + c) * 16;
        const float* K3 = Ks + (b * Cc + c) * 9;
        float fx = K3[0] * (1.0f / 256.0f);
        float fy = K3[4] * (1.0f / 256.0f);
        float cx = K3[2] * (1.0f / 256.0f) - 0.5f;
        float cy = K3[5] * (1.0f / 256.0f) - 0.5f;
        // P = lift(Kn) @ V
        float P[16];
        #pragma unroll
        for (int j = 0; j < 4; ++j) {
            P[0 * 4 + j] = fx * V[0 * 4 + j] + cx * V[2 * 4 + j];
            P[1 * 4 + j] = fy * V[1 * 4 + j] + cy * V[2 * 4 + j];
            P[2 * 4 + j] = V[2 * 4 + j];
            P[3 * 4 + j] = V[3 * 4 + j];
        }
        // invert_SE3(V)
        float IV[16];
        IV[0] = V[0]; IV[1] = V[4]; IV[2] = V[8];
        IV[4] = V[1]; IV[5] = V[5]; IV[6] = V[9];
        IV[8] = V[2]; IV[9] = V[6]; IV[10] = V[10];
        float tx = V[3], ty = V[7], tz = V[11];
        IV[3]  = -(IV[0] * tx + IV[1] * ty + IV[2] * tz);
        IV[7]  = -(IV[4] * tx + IV[5] * ty + IV[6] * tz);
        IV[11] = -(IV[8] * tx + IV[9] * ty + IV[10] * tz);
        IV[12] = 0.f; IV[13] = 0.f; IV[14] = 0.f; IV[15] = 1.f;
        // P_inv = invert_SE3(V) @ lift(invert_K(Kn))
        float ifx = 1.f / fx, ify = 1.f / fy;
        float ncx = -cx * ifx, ncy = -cy * ify;
        float Pi[16];
        #pragma unroll
        for (int i = 0; i < 4; ++i) {
            Pi[i * 4 + 0] = IV[i * 4 + 0] * ifx;
            Pi[i * 4 + 1] = IV[i * 4 + 1] * ify;
            Pi[i * 4 + 2] = IV[i * 4 + 0] * ncx + IV[i * 4 + 1] * ncy + IV[i * 4 + 2];
            Pi[i * 4 + 3] = IV[i * 4 + 3];
        }
        float* o = ws + t * 48;
        #pragma unroll
        for (int i = 0; i < 16; ++i) o[i] = P[i];
        #pragma unroll
        for (int i = 0; i < 4; ++i)
            #pragma unroll
            for (int j = 0; j < 4; ++j) o[16 + i * 4 + j] = P[j * 4 + i];  // P^T
        #pragma unroll
        for (int i = 0; i < 16; ++i) o[32 + i] = Pi[i];
    }
}

__device__ __forceinline__ void matvec_groups(float* x, const float* M, int g0, int g1) {
    #pragma unroll
    for (int g = 0; g < 8; ++g) {
        if (g >= g0 && g < g1) {
            float a0 = x[4 * g + 0], a1 = x[4 * g + 1], a2 = x[4 * g + 2], a3 = x[4 * g + 3];
            x[4 * g + 0] = M[0]  * a0 + M[1]  * a1 + M[2]  * a2 + M[3]  * a3;
            x[4 * g + 1] = M[4]  * a0 + M[5]  * a1 + M[6]  * a2 + M[7]  * a3;
            x[4 * g + 2] = M[8]  * a0 + M[9]  * a1 + M[10] * a2 + M[11] * a3;
            x[4 * g + 3] = M[12] * a0 + M[13] * a1 + M[14] * a2 + M[15] * a3;
        }
    }
}

__global__ __launch_bounds__(BDIM, 2) void prope_attn_kernel(
    const float* __restrict__ q, const float* __restrict__ k, const float* __restrict__ v,
    const float* __restrict__ ws, float* __restrict__ out) {
    __shared__ float KtS[TK * LDSTR];
    __shared__ float VtS[TK * LDSTR];

    const int tid = threadIdx.x;
    const int b = blockIdx.z, h = blockIdx.y;
    const int qrow = blockIdx.x * QROWS + tid;
    const bool valid = qrow < Nc;
    const size_t bh = (size_t)(b * Hc + h);
    const float* trigbase = ws + 384;

    // ---- load + transform own q row into registers ----
    float qr[64];
    if (valid) {
        const float* gq = q + (bh * Nc + qrow) * HDc;
        #pragma unroll
        for (int i = 0; i < 16; ++i) ((float4*)qr)[i] = ((const float4*)gq)[i];
        if (qrow >= EXTRAc) {
            int cam = (qrow - EXTRAc) >> 8;
            const float* M = ws + ((b * Cc + cam) * 3 + 1) * 16;  // Mq = P^T
            float Mr[16];
            #pragma unroll
            for (int i = 0; i < 16; ++i) Mr[i] = M[i];
            matvec_groups(qr, Mr, 0, 8);
            const float* tg = trigbase + qrow * 32;
            #pragma unroll
            for (int f = 0; f < 8; ++f) {
                float c = tg[f], s = tg[8 + f];
                float xa = qr[32 + f], xb = qr[40 + f];
                qr[32 + f] = c * xa + s * xb;
                qr[40 + f] = -s * xa + c * xb;
            }
            #pragma unroll
            for (int f = 0; f < 8; ++f) {
                float c = tg[16 + f], s = tg[24 + f];
                float xa = qr[48 + f], xb = qr[56 + f];
                qr[48 + f] = c * xa + s * xb;
                qr[56 + f] = -s * xa + c * xb;
            }
        }
    }

    float acc[64];
    #pragma unroll
    for (int i = 0; i < 64; ++i) acc[i] = 0.f;
    float mrun = -1e30f, lrun = 0.f;

    // staging role: wave0 (tid<64) stages K, wave1 stages V; 4 threads/row, 16 dims each
    const int srow = (tid & 63) >> 2;
    const int sseg = tid & 3;
    const bool isV = tid >= 64;
    const float* src = isV ? v : k;

    for (int kt = 0; kt < NKT; ++kt) {
        // --- stage into regs + transform ---
        int key = kt * TK + srow;
        float vals[16];
        {
            const float* g = src + (bh * Nc + key) * HDc + sseg * 16;
            #pragma unroll
            for (int i = 0; i < 4; ++i) ((float4*)vals)[i] = ((const float4*)g)[i];
        }
        if (key >= EXTRAc) {
            if (sseg < 2) {
                int cam = (key - EXTRAc) >> 8;
                const float* M = ws + ((b * Cc + cam) * 3 + 2) * 16;  // Mkv = P_inv
                #pragma unroll
                for (int gg = 0; gg < 4; ++gg) {
                    float a0 = vals[4 * gg + 0], a1 = vals[4 * gg + 1];
                    float a2 = vals[4 * gg + 2], a3 = vals[4 * gg + 3];
                    vals[4 * gg + 0] = M[0]  * a0 + M[1]  * a1 + M[2]  * a2 + M[3]  * a3;
                    vals[4 * gg + 1] = M[4]  * a0 + M[5]  * a1 + M[6]  * a2 + M[7]  * a3;
                    vals[4 * gg + 2] = M[8]  * a0 + M[9]  * a1 + M[10] * a2 + M[11] * a3;
                    vals[4 * gg + 3] = M[12] * a0 + M[13] * a1 + M[14] * a2 + M[15] * a3;
                }
            } else {
                const float* tg = trigbase + key * 32 + (sseg == 3 ? 16 : 0);
                #pragma unroll
                for (int f = 0; f < 8; ++f) {
                    float c = tg[f], s = tg[8 + f];
                    float xa = vals[f], xb = vals[8 + f];
                    vals[f]     = c * xa + s * xb;
                    vals[8 + f] = -s * xa + c * xb;
                }
            }
        }
        __syncthreads();  // previous tile's compute done
        {
            float* dst = (isV ? VtS : KtS) + srow * LDSTR + sseg * 16;
            #pragma unroll
            for (int i = 0; i < 4; ++i) ((float4*)dst)[i] = ((float4*)vals)[i];
        }
        __syncthreads();  // staging visible

        // --- compute tile ---
        if (valid) {
            float sv[TK];
            float tmax = -1e30f;
            #pragma unroll
            for (int kk = 0; kk < TK; ++kk) {
                const float4* kr = (const float4*)&KtS[kk * LDSTR];
                float s0 = 0.f, s1 = 0.f, s2 = 0.f, s3 = 0.f;
                #pragma unroll
                for (int i = 0; i < 4; ++i) {
                    float4 k0 = kr[4 * i + 0], k1 = kr[4 * i + 1];
                    float4 k2 = kr[4 * i + 2], k3 = kr[4 * i + 3];
                    float4 q0 = ((const float4*)qr)[4 * i + 0], q1 = ((const float4*)qr)[4 * i + 1];
                    float4 q2 = ((const float4*)qr)[4 * i + 2], q3 = ((const float4*)qr)[4 * i + 3];
                    s0 += q0.x * k0.x + q0.y * k0.y + q0.z * k0.z + q0.w * k0.w;
                    s1 += q1.x * k1.x + q1.y * k1.y + q1.z * k1.z + q1.w * k1.w;
                    s2 += q2.x * k2.x + q2.y * k2.y + q2.z * k2.z + q2.w * k2.w;
                    s3 += q3.x * k3.x + q3.y * k3.y + q3.z * k3.z + q3.w * k3.w;
                }
                float s = ((s0 + s1) + (s2 + s3)) * 0.125f;
                sv[kk] = s;
                tmax = fmaxf(tmax, s);
            }
            float nm = fmaxf(mrun, tmax);
            float corr = __expf(mrun - nm);
            mrun = nm;
            lrun *= corr;
            #pragma unroll
            for (int i = 0; i < 64; ++i) acc[i] *= corr;
            #pragma unroll
            for (int kk = 0; kk < TK; ++kk) {
                float p = __expf(sv[kk] - nm);
                lrun += p;
                const float4* vr = (const float4*)&VtS[kk * LDSTR];
                #pragma unroll
                for (int i = 0; i < 16; ++i) {
                    float4 vv = vr[i];
                    acc[4 * i + 0] += p * vv.x;
                    acc[4 * i + 1] += p * vv.y;
                    acc[4 * i + 2] += p * vv.z;
                    acc[4 * i + 3] += p * vv.w;
                }
            }
        }
    }

    // ---- epilogue: normalize, inverse transform with Mo, store ----
    if (valid) {
        float inv_l = 1.f / lrun;
        #pragma unroll
        for (int i = 0; i < 64; ++i) acc[i] *= inv_l;
        if (qrow >= EXTRAc) {
            int cam = (qrow - EXTRAc) >> 8;
            const float* M = ws + ((b * Cc + cam) * 3 + 0) * 16;  // Mo = P
            float Mr[16];
            #pragma unroll
            for (int i = 0; i < 16; ++i) Mr[i] = M[i];
            matvec_groups(acc, Mr, 0, 8);
            const float* tg = trigbase + qrow * 32;
            #pragma unroll
            for (int f = 0; f < 8; ++f) {  // inverse rope x
                float c = tg[f], s = tg[8 + f];
                float xa = acc[32 + f], xb = acc[40 + f];
                acc[32 + f] = c * xa - s * xb;
                acc[40 + f] = s * xa + c * xb;
            }
            #pragma unroll
            for (int f = 0; f < 8; ++f) {  // inverse rope y
                float c = tg[16 + f], s = tg[24 + f];
                float xa = acc[48 + f], xb = acc[56 + f];
                acc[48 + f] = c * xa - s * xb;
                acc[56 + f] = s * xa + c * xb;
            }
        }
        float* go = out + (bh * Nc + qrow) * HDc;
        #pragma unroll
        for (int i = 0; i < 16; ++i) ((float4*)go)[i] = ((const float4*)acc)[i];
    }
}

extern "C" void kernel_launch(void* const* d_in, const int* in_sizes, int n_in,
                              void* d_out, int out_size, void* d_ws, size_t ws_size,
                              hipStream_t stream) {
    const float* q        = (const float*)d_in[0];
    const float* k        = (const float*)d_in[1];
    const float* v        = (const float*)d_in[2];
    const float* viewmats = (const float*)d_in[3];
    const float* Ks       = (const float*)d_in[4];
    float* ws  = (float*)d_ws;
    float* out = (float*)d_out;

    prope_precompute_kernel<<<(Nc + 255) / 256, 256, 0, stream>>>(viewmats, Ks, ws);

    dim3 grid(NQT, Hc, Bc);
    prope_attn_kernel<<<grid, BDIM, 0, stream>>>(q, k, v, ws, out);
}

// Round 2
// 70.277 us; speedup vs baseline: 10.4406x; 10.4406x over previous
//
#include <hip/hip_runtime.h>
#include <math.h>

typedef _Float16 f16;
typedef _Float16 f16x8 __attribute__((ext_vector_type(8)));
typedef float f32x4 __attribute__((ext_vector_type(4)));

constexpr int Bc = 2, Hc = 16, Cc = 4, PXc = 16, PYc = 16, EXTRAc = 64, HDc = 64;
constexpr int Nc = Cc * PXc * PYc + EXTRAc;   // 1088
constexpr int BH = Bc * Hc;                   // 32
constexpr int KT = 64;                        // keys per tile
constexpr int QT = 64;                        // q rows per block
constexpr int NKT = Nc / KT;                  // 17 (exact)
constexpr int OLST = 72;                      // epilogue LDS row stride (floats)

// ws layout (bytes):
//   [0      .. 1536)    mats fp32: [b][c][which][16], which: 0=P(Mo), 1=P^T(Mq), 2=P_inv(Mkv)
//   [1536   .. 140800)  trig fp32: [n][32] = cosx[8], sinx[8], cosy[8], siny[8]
//   [262144 .. )        Qf16 [bh][n][64], Kf16 [bh][n][64], Vt f16 [bh][d][n]
constexpr size_t TRIG_OFF_F = 384;                       // float index
constexpr size_t QF_OFF  = 262144;                       // bytes
constexpr size_t TENS_SZ = (size_t)BH * Nc * HDc * 2;    // 4456448 bytes
constexpr size_t KF_OFF  = QF_OFF + TENS_SZ;
constexpr size_t VT_OFF  = KF_OFF + TENS_SZ;

// ---------------- precompute: mats + trig ----------------
__global__ void prope_precompute_kernel(const float* __restrict__ viewmats,
                                        const float* __restrict__ Ks,
                                        float* __restrict__ ws) {
    int t = blockIdx.x * blockDim.x + threadIdx.x;
    if (t < Nc) {
        float* trig = ws + TRIG_OFF_F + t * 32;
        if (t < EXTRAc) {
            #pragma unroll
            for (int f = 0; f < 8; ++f) {
                trig[f] = 1.f; trig[8 + f] = 0.f; trig[16 + f] = 1.f; trig[24 + f] = 0.f;
            }
        } else {
            int sidx = t - EXTRAc;
            float px = (float)(sidx & (PXc - 1));
            float py = (float)((sidx >> 4) & (PYc - 1));
            #pragma unroll
            for (int f = 0; f < 8; ++f) {
                float freq = powf(100.0f, -(float)f * 0.125f);
                float ax = px * freq, ay = py * freq;
                trig[f]      = cosf(ax);
                trig[8 + f]  = sinf(ax);
                trig[16 + f] = cosf(ay);
                trig[24 + f] = sinf(ay);
            }
        }
    }
    if (t < Bc * Cc) {
        int b = t / Cc, c = t % Cc;
        const float* V  = viewmats + (b * Cc + c) * 16;
        const float* K3 = Ks + (b * Cc + c) * 9;
        float fx = K3[0] * (1.0f / 256.0f);
        float fy = K3[4] * (1.0f / 256.0f);
        float cx = K3[2] * (1.0f / 256.0f) - 0.5f;
        float cy = K3[5] * (1.0f / 256.0f) - 0.5f;
        float P[16];
        #pragma unroll
        for (int j = 0; j < 4; ++j) {
            P[0 * 4 + j] = fx * V[0 * 4 + j] + cx * V[2 * 4 + j];
            P[1 * 4 + j] = fy * V[1 * 4 + j] + cy * V[2 * 4 + j];
            P[2 * 4 + j] = V[2 * 4 + j];
            P[3 * 4 + j] = V[3 * 4 + j];
        }
        float IV[16];
        IV[0] = V[0]; IV[1] = V[4]; IV[2] = V[8];
        IV[4] = V[1]; IV[5] = V[5]; IV[6] = V[9];
        IV[8] = V[2]; IV[9] = V[6]; IV[10] = V[10];
        float tx = V[3], ty = V[7], tz = V[11];
        IV[3]  = -(IV[0] * tx + IV[1] * ty + IV[2] * tz);
        IV[7]  = -(IV[4] * tx + IV[5] * ty + IV[6] * tz);
        IV[11] = -(IV[8] * tx + IV[9] * ty + IV[10] * tz);
        IV[12] = 0.f; IV[13] = 0.f; IV[14] = 0.f; IV[15] = 1.f;
        float ifx = 1.f / fx, ify = 1.f / fy;
        float ncx = -cx * ifx, ncy = -cy * ify;
        float Pi[16];
        #pragma unroll
        for (int i = 0; i < 4; ++i) {
            Pi[i * 4 + 0] = IV[i * 4 + 0] * ifx;
            Pi[i * 4 + 1] = IV[i * 4 + 1] * ify;
            Pi[i * 4 + 2] = IV[i * 4 + 0] * ncx + IV[i * 4 + 1] * ncy + IV[i * 4 + 2];
            Pi[i * 4 + 3] = IV[i * 4 + 3];
        }
        float* o = ws + t * 48;
        #pragma unroll
        for (int i = 0; i < 16; ++i) o[i] = P[i];
        #pragma unroll
        for (int i = 0; i < 4; ++i)
            #pragma unroll
            for (int j = 0; j < 4; ++j) o[16 + i * 4 + j] = P[j * 4 + i];  // P^T
        #pragma unroll
        for (int i = 0; i < 16; ++i) o[32 + i] = Pi[i];
    }
}

// forward transform of one 16-dim segment of a token row
__device__ __forceinline__ void xform_fwd_seg(float* v16, int seg, int n, int b, int which,
                                              const float* __restrict__ wsf) {
    if (n < EXTRAc) return;
    int cam = (n - EXTRAc) >> 8;
    if (seg < 2) {
        const float* M = wsf + ((b * Cc + cam) * 3 + which) * 16;
        #pragma unroll
        for (int g = 0; g < 4; ++g) {
            float a0 = v16[4 * g], a1 = v16[4 * g + 1], a2 = v16[4 * g + 2], a3 = v16[4 * g + 3];
            v16[4 * g + 0] = M[0]  * a0 + M[1]  * a1 + M[2]  * a2 + M[3]  * a3;
            v16[4 * g + 1] = M[4]  * a0 + M[5]  * a1 + M[6]  * a2 + M[7]  * a3;
            v16[4 * g + 2] = M[8]  * a0 + M[9]  * a1 + M[10] * a2 + M[11] * a3;
            v16[4 * g + 3] = M[12] * a0 + M[13] * a1 + M[14] * a2 + M[15] * a3;
        }
    } else {
        const float* tg = wsf + TRIG_OFF_F + n * 32 + (seg == 3 ? 16 : 0);
        #pragma unroll
        for (int f = 0; f < 8; ++f) {
            float c = tg[f], s = tg[8 + f];
            float xa = v16[f], xb = v16[8 + f];
            v16[f]     = c * xa + s * xb;
            v16[8 + f] = -s * xa + c * xb;
        }
    }
}

// ---------------- transform Q,K -> f16 (row layout) ----------------
__global__ void xform_qk_kernel(const float* __restrict__ q, const float* __restrict__ k,
                                float* __restrict__ ws) {
    int id = blockIdx.x * 256 + threadIdx.x;  // 2*BH*Nc*4 tasks exactly
    int seg = id & 3;
    int rid = id >> 2;
    int tensor = rid / (BH * Nc);   // 0=Q, 1=K
    int row = rid - tensor * (BH * Nc);
    int n = row % Nc;
    int b = (row / Nc) >> 4;        // bh / Hc
    const float* src = (tensor ? k : q) + (size_t)row * 64 + seg * 16;
    float vals[16];
    #pragma unroll
    for (int i = 0; i < 4; ++i) ((float4*)vals)[i] = ((const float4*)src)[i];
    xform_fwd_seg(vals, seg, n, b, tensor ? 2 : 1, ws);
    float scale = tensor ? 1.0f : 0.125f;   // fold 1/sqrt(64) into Q
    f16 o[16];
    #pragma unroll
    for (int i = 0; i < 16; ++i) o[i] = (f16)(vals[i] * scale);
    char* dstb = (char*)ws + (tensor ? KF_OFF : QF_OFF) + ((size_t)row * 64 + seg * 16) * 2;
    ((float4*)dstb)[0] = ((float4*)o)[0];
    ((float4*)dstb)[1] = ((float4*)o)[1];
}

// ---------------- transform V -> f16 transposed [bh][d][n] ----------------
__global__ void xform_v_kernel(const float* __restrict__ v, float* __restrict__ ws) {
    __shared__ f16 tile[64][72];
    int bh = blockIdx.y;
    int b = bh >> 4;
    int n0 = blockIdx.x * 64;
    int t = threadIdx.x;
    {
        int r = t >> 2, seg = t & 3;
        int n = n0 + r;
        const float* src = v + ((size_t)bh * Nc + n) * 64 + seg * 16;
        float vals[16];
        #pragma unroll
        for (int i = 0; i < 4; ++i) ((float4*)vals)[i] = ((const float4*)src)[i];
        xform_fwd_seg(vals, seg, n, b, 2, ws);
        #pragma unroll
        for (int i = 0; i < 16; ++i) tile[r][seg * 16 + i] = (f16)vals[i];
    }
    __syncthreads();
    {
        int d = t >> 2, ks = t & 3;
        f16 o[16];
        #pragma unroll
        for (int j = 0; j < 16; ++j) o[j] = tile[ks * 16 + j][d];
        char* dstb = (char*)ws + VT_OFF + (((size_t)bh * 64 + d) * Nc + n0 + ks * 16) * 2;
        ((float4*)dstb)[0] = ((float4*)o)[0];
        ((float4*)dstb)[1] = ((float4*)o)[1];
    }
}

// ---------------- fused MFMA flash attention ----------------
__global__ __launch_bounds__(256, 2) void prope_attn_mfma_kernel(
    const float* __restrict__ ws, float* __restrict__ out) {
    __shared__ float4 smem4[40960 / 16];
    char* smem = (char*)smem4;
    char* kbuf0 = smem;             // 8KB each
    char* kbuf1 = smem + 8192;
    char* vbuf0 = smem + 16384;
    char* vbuf1 = smem + 24576;

    const int tid = threadIdx.x;
    const int bh = blockIdx.y;
    const int qt0 = blockIdx.x * QT;
    const int wv = tid >> 6, lane = tid & 63;
    const int qg = lane >> 4, qc = lane & 15;
    char* pb = smem + 32768 + wv * 2048;    // per-wave P buffer 16x64 f16

    const f16* qf = (const f16*)((const char*)ws + QF_OFF);
    const f16* kf = (const f16*)((const char*)ws + KF_OFF);
    const f16* vt = (const f16*)((const char*)ws + VT_OFF);

    // Q A-fragments: row = lane&15, k = (lane>>4)*8+j
    const f16* qrowp = qf + ((size_t)bh * Nc + qt0 + wv * 16 + qc) * 64;
    const f16x8 qa0 = *(const f16x8*)(qrowp + qg * 8);
    const f16x8 qa1 = *(const f16x8*)(qrowp + 32 + qg * 8);

    // staging: thread t covers 32B of row (t>>2), byte seg (t&3)*32
    const int srow = tid >> 2;
    const int sbyte = (tid & 3) * 32;
    const f16* kgbase = kf + (size_t)bh * Nc * 64;
    const f16* vtbase = vt + (size_t)bh * 64 * Nc;
    const int swz = (srow & 7) << 4;
    const int wa0 = (srow * 128 + sbyte) ^ swz;
    const int wa1 = (srow * 128 + sbyte + 16) ^ swz;

    float4 kr0, kr1, vr0, vr1;
    auto LOADS = [&](int kt) {
        const char* kp = (const char*)(kgbase + (size_t)(kt * KT + srow) * 64) + sbyte;
        kr0 = *(const float4*)kp;
        kr1 = *(const float4*)(kp + 16);
        const char* vp = (const char*)(vtbase + (size_t)srow * Nc + kt * KT) + sbyte;
        vr0 = *(const float4*)vp;
        vr1 = *(const float4*)(vp + 16);
    };
    auto WRITE = [&](char* kb, char* vb) {
        *(float4*)(kb + wa0) = kr0;
        *(float4*)(kb + wa1) = kr1;
        *(float4*)(vb + wa0) = vr0;
        *(float4*)(vb + wa1) = vr1;
    };

    f32x4 O[4];
    #pragma unroll
    for (int dg = 0; dg < 4; ++dg) O[dg] = (f32x4){0.f, 0.f, 0.f, 0.f};
    float mrun[4], lrun[4];
    #pragma unroll
    for (int r = 0; r < 4; ++r) { mrun[r] = -1e30f; lrun[r] = 0.f; }

    LOADS(0);
    WRITE(kbuf0, kbuf0 + 16384);   // kbuf0/vbuf0
    __syncthreads();

    for (int kt = 0; kt < NKT; ++kt) {
        const char* kb_ = (kt & 1) ? kbuf1 : kbuf0;
        const char* vb_ = (kt & 1) ? vbuf1 : vbuf0;
        if (kt + 1 < NKT) LOADS(kt + 1);

        // --- QK^T: S[kg] covers keys kg*16..+15, q rows (lane>>4)*4+r ---
        f32x4 S[4];
        #pragma unroll
        for (int kg = 0; kg < 4; ++kg) {
            int row = kg * 16 + qc;
            int a0 = (row * 128 + qg * 16) ^ ((row & 7) << 4);
            f16x8 b0 = *(const f16x8*)(kb_ + a0);
            f16x8 b1 = *(const f16x8*)(kb_ + (a0 ^ 64));
            f32x4 s = __builtin_amdgcn_mfma_f32_16x16x32_f16(qa0, b0, (f32x4){0.f, 0.f, 0.f, 0.f}, 0, 0, 0);
            S[kg] = __builtin_amdgcn_mfma_f32_16x16x32_f16(qa1, b1, s, 0, 0, 0);
        }

        // --- online softmax (per lane: 4 q-rows, 4 keys each) ---
        float corr[4], psum[4];
        #pragma unroll
        for (int r = 0; r < 4; ++r) {
            float tm = fmaxf(fmaxf(S[0][r], S[1][r]), fmaxf(S[2][r], S[3][r]));
            tm = fmaxf(tm, __shfl_xor(tm, 1, 64));
            tm = fmaxf(tm, __shfl_xor(tm, 2, 64));
            tm = fmaxf(tm, __shfl_xor(tm, 4, 64));
            tm = fmaxf(tm, __shfl_xor(tm, 8, 64));
            float nm = fmaxf(mrun[r], tm);
            corr[r] = __expf(mrun[r] - nm);
            mrun[r] = nm;
            psum[r] = 0.f;
        }
        f16 pv[4][4];
        #pragma unroll
        for (int kg = 0; kg < 4; ++kg)
            #pragma unroll
            for (int r = 0; r < 4; ++r) {
                float p = __expf(S[kg][r] - mrun[r]);
                psum[r] += p;
                pv[kg][r] = (f16)p;
            }
        // write P (C layout) to LDS, swizzled
        #pragma unroll
        for (int kg = 0; kg < 4; ++kg)
            #pragma unroll
            for (int r = 0; r < 4; ++r) {
                int qq = qg * 4 + r;
                int a = (qq * 128 + (kg * 16 + qc) * 2) ^ ((qq & 7) << 4);
                *(f16*)(pb + a) = pv[kg][r];
            }
        // read P back as A-fragments (row = lane&15 = q, k = keys)
        int pa0a = (qc * 128 + qg * 16) ^ ((qc & 7) << 4);
        f16x8 pa0 = *(const f16x8*)(pb + pa0a);
        f16x8 pa1 = *(const f16x8*)(pb + (pa0a ^ 64));

        // rescale O
        #pragma unroll
        for (int dg = 0; dg < 4; ++dg)
            #pragma unroll
            for (int r = 0; r < 4; ++r) O[dg][r] *= corr[r];

        // --- PV: B from Vt (row = dim) ---
        #pragma unroll
        for (int dg = 0; dg < 4; ++dg) {
            int row = dg * 16 + qc;
            int a0 = (row * 128 + qg * 16) ^ ((row & 7) << 4);
            f16x8 v0 = *(const f16x8*)(vb_ + a0);
            f16x8 v1 = *(const f16x8*)(vb_ + (a0 ^ 64));
            O[dg] = __builtin_amdgcn_mfma_f32_16x16x32_f16(pa0, v0, O[dg], 0, 0, 0);
            O[dg] = __builtin_amdgcn_mfma_f32_16x16x32_f16(pa1, v1, O[dg], 0, 0, 0);
        }

        // lrun update
        #pragma unroll
        for (int r = 0; r < 4; ++r) {
            float ps = psum[r];
            ps += __shfl_xor(ps, 1, 64);
            ps += __shfl_xor(ps, 2, 64);
            ps += __shfl_xor(ps, 4, 64);
            ps += __shfl_xor(ps, 8, 64);
            lrun[r] = lrun[r] * corr[r] + ps;
        }

        if (kt + 1 < NKT) {
            char* kbn = (kt & 1) ? kbuf0 : kbuf1;
            WRITE(kbn, kbn + 16384);
        }
        __syncthreads();
    }

    // ---- epilogue: O -> LDS (fp32), inverse transform, store ----
    float* ol = (float*)smem;   // 64 x OLST floats = 18432 B
    #pragma unroll
    for (int dg = 0; dg < 4; ++dg)
        #pragma unroll
        for (int r = 0; r < 4; ++r) {
            int qq = wv * 16 + qg * 4 + r;
            ol[qq * OLST + dg * 16 + qc] = O[dg][r] / lrun[r];
        }
    __syncthreads();
    {
        int r = tid >> 2, seg = tid & 3;
        int n = qt0 + r;
        int b = bh >> 4;
        float vals[16];
        #pragma unroll
        for (int j = 0; j < 16; ++j) vals[j] = ol[r * OLST + seg * 16 + j];
        if (n >= EXTRAc) {
            int cam = (n - EXTRAc) >> 8;
            if (seg < 2) {
                const float* M = ws + ((b * Cc + cam) * 3 + 0) * 16;  // Mo = P
                #pragma unroll
                for (int g = 0; g < 4; ++g) {
                    float a0 = vals[4 * g], a1 = vals[4 * g + 1], a2 = vals[4 * g + 2], a3 = vals[4 * g + 3];
                    vals[4 * g + 0] = M[0]  * a0 + M[1]  * a1 + M[2]  * a2 + M[3]  * a3;
                    vals[4 * g + 1] = M[4]  * a0 + M[5]  * a1 + M[6]  * a2 + M[7]  * a3;
                    vals[4 * g + 2] = M[8]  * a0 + M[9]  * a1 + M[10] * a2 + M[11] * a3;
                    vals[4 * g + 3] = M[12] * a0 + M[13] * a1 + M[14] * a2 + M[15] * a3;
                }
            } else {
                const float* tg = ws + TRIG_OFF_F + n * 32 + (seg == 3 ? 16 : 0);
                #pragma unroll
                for (int f = 0; f < 8; ++f) {   // inverse rope
                    float c = tg[f], s = tg[8 + f];
                    float xa = vals[f], xb = vals[8 + f];
                    vals[f]     = c * xa - s * xb;
                    vals[8 + f] = s * xa + c * xb;
                }
            }
        }
        float* go = out + ((size_t)bh * Nc + n) * 64 + seg * 16;
        #pragma unroll
        for (int i = 0; i < 4; ++i) ((float4*)go)[i] = ((const float4*)vals)[i];
    }
}

extern "C" void kernel_launch(void* const* d_in, const int* in_sizes, int n_in,
                              void* d_out, int out_size, void* d_ws, size_t ws_size,
                              hipStream_t stream) {
    const float* q        = (const float*)d_in[0];
    const float* k        = (const float*)d_in[1];
    const float* v        = (const float*)d_in[2];
    const float* viewmats = (const float*)d_in[3];
    const float* Ks       = (const float*)d_in[4];
    float* ws  = (float*)d_ws;
    float* out = (float*)d_out;

    prope_precompute_kernel<<<(Nc + 255) / 256, 256, 0, stream>>>(viewmats, Ks, ws);

    // Q,K transform: 2 tensors * BH*Nc rows * 4 segs / 256 = 1088 blocks
    xform_qk_kernel<<<(2 * BH * Nc * 4) / 256, 256, 0, stream>>>(q, k, ws);
    xform_v_kernel<<<dim3(NKT, BH), 256, 0, stream>>>(v, ws);

    prope_attn_mfma_kernel<<<dim3(NKT, BH), 256, 0, stream>>>(ws, out);
}

// Round 4
// 54.882 us; speedup vs baseline: 13.3693x; 1.2805x over previous
//
#include <hip/hip_runtime.h>
#include <math.h>

typedef _Float16 f16;
typedef _Float16 f16x8 __attribute__((ext_vector_type(8)));
typedef __fp16 h16x2 __attribute__((ext_vector_type(2)));
typedef float f32x16 __attribute__((ext_vector_type(16)));
typedef unsigned int u32;
typedef u32 u32x4 __attribute__((ext_vector_type(4)));

constexpr int Bc = 2, Hc = 16, Cc = 4, PXc = 16, PYc = 16, EXTRAc = 64, HDc = 64;
constexpr int Nc = Cc * PXc * PYc + EXTRAc;   // 1088
constexpr int BH = Bc * Hc;                   // 32
constexpr int KT = 64;                        // keys per tile
constexpr int NKT = Nc / KT;                  // 17
constexpr int KS = 4;                         // key splits

// ws layout (bytes)
constexpr size_t TENS_SZ  = (size_t)BH * Nc * HDc * 2;       // 4,456,448
constexpr size_t QF_OFF   = 0;
constexpr size_t KF_OFF   = QF_OFF + TENS_SZ;
constexpr size_t VT_OFF   = KF_OFF + TENS_SZ;
constexpr size_t PART_OFF = VT_OFF + TENS_SZ;                // KS * TENS_SZ f16 partials
constexpr size_t ML_OFF   = PART_OFF + (size_t)KS * TENS_SZ; // KS*BH*Nc float2

__device__ const float FREQS[8] = {1.0f, 0.5623413252f, 0.31622776601f, 0.17782794100f,
                                   0.1f, 0.05623413252f, 0.031622776602f, 0.017782794100f};
constexpr float QSCALE = 0.125f * 1.4426950408889634f;   // 1/sqrt(64) * log2(e)

// ---- inline camera matrices ----
__device__ __forceinline__ void compute_M(float* M, const float* __restrict__ vm,
                                          const float* __restrict__ Ks3, int b, int cam, int which) {
    const float* V  = vm + (b * Cc + cam) * 16;
    const float* K3 = Ks3 + (b * Cc + cam) * 9;
    float fx = K3[0] * (1.0f / 256.0f);
    float fy = K3[4] * (1.0f / 256.0f);
    float cx = K3[2] * (1.0f / 256.0f) - 0.5f;
    float cy = K3[5] * (1.0f / 256.0f) - 0.5f;
    if (which == 2) {  // P_inv = invert_SE3(V) @ lift(invert_K(Kn))
        float IV[16];
        IV[0] = V[0]; IV[1] = V[4]; IV[2] = V[8];
        IV[4] = V[1]; IV[5] = V[5]; IV[6] = V[9];
        IV[8] = V[2]; IV[9] = V[6]; IV[10] = V[10];
        float tx = V[3], ty = V[7], tz = V[11];
        IV[3]  = -(IV[0] * tx + IV[1] * ty + IV[2] * tz);
        IV[7]  = -(IV[4] * tx + IV[5] * ty + IV[6] * tz);
        IV[11] = -(IV[8] * tx + IV[9] * ty + IV[10] * tz);
        IV[12] = 0.f; IV[13] = 0.f; IV[14] = 0.f; IV[15] = 1.f;
        float ifx = 1.f / fx, ify = 1.f / fy;
        float ncx = -cx * ifx, ncy = -cy * ify;
        #pragma unroll
        for (int i = 0; i < 4; ++i) {
            M[i * 4 + 0] = IV[i * 4 + 0] * ifx;
            M[i * 4 + 1] = IV[i * 4 + 1] * ify;
            M[i * 4 + 2] = IV[i * 4 + 0] * ncx + IV[i * 4 + 1] * ncy + IV[i * 4 + 2];
            M[i * 4 + 3] = IV[i * 4 + 3];
        }
    } else {
        float P[16];
        #pragma unroll
        for (int j = 0; j < 4; ++j) {
            P[0 * 4 + j] = fx * V[0 * 4 + j] + cx * V[2 * 4 + j];
            P[1 * 4 + j] = fy * V[1 * 4 + j] + cy * V[2 * 4 + j];
            P[2 * 4 + j] = V[2 * 4 + j];
            P[3 * 4 + j] = V[3 * 4 + j];
        }
        if (which == 0) {
            #pragma unroll
            for (int i = 0; i < 16; ++i) M[i] = P[i];
        } else {
            #pragma unroll
            for (int i = 0; i < 4; ++i)
                #pragma unroll
                for (int j = 0; j < 4; ++j) M[i * 4 + j] = P[j * 4 + i];
        }
    }
}

// forward/inverse transform of one 16-dim segment of token n
template <bool INV>
__device__ __forceinline__ void xf_seg(float* v16, int seg, int n, int b, int which,
                                       const float* __restrict__ vm, const float* __restrict__ Ks3) {
    if (n < EXTRAc) return;
    int sidx = n - EXTRAc;
    int cam = sidx >> 8;
    if (seg < 2) {
        float M[16];
        compute_M(M, vm, Ks3, b, cam, which);
        #pragma unroll
        for (int g = 0; g < 4; ++g) {
            float a0 = v16[4 * g], a1 = v16[4 * g + 1], a2 = v16[4 * g + 2], a3 = v16[4 * g + 3];
            v16[4 * g + 0] = M[0]  * a0 + M[1]  * a1 + M[2]  * a2 + M[3]  * a3;
            v16[4 * g + 1] = M[4]  * a0 + M[5]  * a1 + M[6]  * a2 + M[7]  * a3;
            v16[4 * g + 2] = M[8]  * a0 + M[9]  * a1 + M[10] * a2 + M[11] * a3;
            v16[4 * g + 3] = M[12] * a0 + M[13] * a1 + M[14] * a2 + M[15] * a3;
        }
    } else {
        float pos = (seg == 2) ? (float)(sidx & (PXc - 1)) : (float)((sidx >> 4) & (PYc - 1));
        #pragma unroll
        for (int f = 0; f < 8; ++f) {
            float s, c;
            __sincosf(pos * FREQS[f], &s, &c);
            float xa = v16[f], xb = v16[8 + f];
            if (INV) {
                v16[f]     = c * xa - s * xb;
                v16[8 + f] = s * xa + c * xb;
            } else {
                v16[f]     = c * xa + s * xb;
                v16[8 + f] = -s * xa + c * xb;
            }
        }
    }
}

__device__ __forceinline__ u32 pkh(float a, float b) {
    h16x2 r = __builtin_amdgcn_cvt_pkrtz(a, b);
    return __builtin_bit_cast(u32, r);
}

__device__ __forceinline__ void gld16(const void* g, void* l) {
    __builtin_amdgcn_global_load_lds((const __attribute__((address_space(1))) unsigned int*)g,
                                     (__attribute__((address_space(3))) unsigned int*)l, 16, 0, 0);
}

__device__ __forceinline__ f32x16 zero16() {
    f32x16 z = {0.f,0.f,0.f,0.f,0.f,0.f,0.f,0.f,0.f,0.f,0.f,0.f,0.f,0.f,0.f,0.f};
    return z;
}

// ---------------- xform: Q,K (row f16) + V (transposed f16), K/Vt tile-swizzled ----------------
__global__ void prope_xform_kernel(const float* __restrict__ q, const float* __restrict__ k,
                                   const float* __restrict__ v,
                                   const float* __restrict__ viewmats, const float* __restrict__ Ks,
                                   char* __restrict__ wsb) {
    __shared__ f16 tile[64][72];
    if (blockIdx.x < 1088) {   // ---- Q/K path ----
        int id = blockIdx.x * 256 + threadIdx.x;
        int seg = id & 3;
        int rid = id >> 2;                 // < 69632
        int tensor = rid / (BH * Nc);      // 0=Q, 1=K
        int row = rid - tensor * (BH * Nc);
        int n = row % Nc;
        int b = (row / Nc) >> 4;
        const float* src = (tensor ? k : q) + (size_t)row * 64 + seg * 16;
        float vals[16];
        #pragma unroll
        for (int i = 0; i < 4; ++i) ((float4*)vals)[i] = ((const float4*)src)[i];
        xf_seg<false>(vals, seg, n, b, tensor ? 2 : 1, viewmats, Ks);
        float scale = tensor ? 1.0f : QSCALE;
        f16 o[16];
        #pragma unroll
        for (int i = 0; i < 16; ++i) o[i] = (f16)(vals[i] * scale);
        if (tensor == 0) {
            char* dst = wsb + QF_OFF + (size_t)row * 128 + seg * 32;
            ((float4*)dst)[0] = ((float4*)o)[0];
            ((float4*)dst)[1] = ((float4*)o)[1];
        } else {
            int r = n & 63;                // tile row
            char* base = wsb + KF_OFF + (size_t)row * 128;
            *(float4*)(base + 16 * ((2 * seg)     ^ (r & 7))) = ((float4*)o)[0];
            *(float4*)(base + 16 * ((2 * seg + 1) ^ (r & 7))) = ((float4*)o)[1];
        }
    } else {                   // ---- V path: transpose + swizzle ----
        int vb = blockIdx.x - 1088;
        int kt = vb >> 5, bh = vb & 31;
        int b = bh >> 4;
        int t = threadIdx.x;
        {
            int r = t >> 2, seg = t & 3;
            int n = kt * 64 + r;
            const float* src = v + ((size_t)bh * Nc + n) * 64 + seg * 16;
            float vals[16];
            #pragma unroll
            for (int i = 0; i < 4; ++i) ((float4*)vals)[i] = ((const float4*)src)[i];
            xf_seg<false>(vals, seg, n, b, 2, viewmats, Ks);
            #pragma unroll
            for (int i = 0; i < 16; ++i) tile[r][seg * 16 + i] = (f16)vals[i];
        }
        __syncthreads();
        {
            int d = t >> 2, ks = t & 3;
            f16 o[16];
            #pragma unroll
            for (int j = 0; j < 16; ++j) o[j] = tile[ks * 16 + j][d];
            char* base = wsb + VT_OFF + (((size_t)bh * 64 + d) * Nc + kt * 64) * 2;
            *(float4*)(base + 16 * ((2 * ks)     ^ (d & 7))) = ((float4*)o)[0];
            *(float4*)(base + 16 * ((2 * ks + 1) ^ (d & 7))) = ((float4*)o)[1];
        }
    }
}

// ---------------- MFMA flash attention (swapped QK^T, 32x32x16) ----------------
__global__ __launch_bounds__(128, 3) void prope_attn_mfma_kernel(
    const char* __restrict__ wsb, char* __restrict__ partO, float* __restrict__ partML) {
    __shared__ char smem[32768];   // 2 x (K 8KB + V 8KB)

    const int tid = threadIdx.x;
    const int wv = tid >> 6, lane = tid & 63;
    const int q = lane & 31, h = lane >> 5;
    const int qt = blockIdx.x, bh = blockIdx.y, z = blockIdx.z;
    const int ts = (NKT * z) / KS, te = (NKT * (z + 1)) / KS;
    const int qrow = qt * 64 + wv * 32 + q;

    const char* kfb = wsb + KF_OFF + (size_t)bh * Nc * 128;
    const char* vtb = wsb + VT_OFF + (size_t)bh * 64 * (Nc * 2);
    const char* qfb = wsb + QF_OFF + ((size_t)bh * Nc + qrow) * 128;

    // Q B-fragments: lane q = col, k-dims 16c+8h..+7
    f16x8 qb[4];
    #pragma unroll
    for (int c = 0; c < 4; ++c) qb[c] = *(const f16x8*)(qfb + c * 32 + h * 16);

    auto stage = [&](int bsel, int t) {
        char* dst = smem + bsel * 16384 + (wv ? 8192 : 0);
        if (wv == 0) {
            const char* src = kfb + (size_t)t * 8192;
            #pragma unroll
            for (int j = 0; j < 8; ++j)
                gld16(src + j * 1024 + lane * 16, dst + j * 1024);
        } else {
            const char* src = vtb + t * 128 + (lane & 7) * 16;
            #pragma unroll
            for (int j = 0; j < 8; ++j)
                gld16(src + (size_t)(j * 8 + (lane >> 3)) * (Nc * 2), dst + j * 1024);
        }
    };

    f32x16 o0 = zero16(), o1 = zero16();
    float mrun = -1e30f, lrun = 0.f;

    stage(0, ts);
    __syncthreads();

    for (int it = ts; it < te; ++it) {
        const int cur = (it - ts) & 1;
        if (it + 1 < te) stage(cur ^ 1, it + 1);
        const char* kb = smem + cur * 16384;
        const char* vb = kb + 8192;

        // --- S^T = K . Q : rows=keys, cols=q ---
        f32x16 s0 = zero16(), s1 = zero16();
        #pragma unroll
        for (int c = 0; c < 4; ++c) {
            int col = c * 32 + h * 16;
            int r0 = q, r1 = 32 + q;
            f16x8 a0 = *(const f16x8*)(kb + ((r0 * 128 + col) ^ ((r0 & 7) << 4)));
            f16x8 a1 = *(const f16x8*)(kb + ((r1 * 128 + col) ^ ((r1 & 7) << 4)));
            s0 = __builtin_amdgcn_mfma_f32_32x32x16_f16(a0, qb[c], s0, 0, 0, 0);
            s1 = __builtin_amdgcn_mfma_f32_32x32x16_f16(a1, qb[c], s1, 0, 0, 0);
        }

        // --- online softmax: per-lane scalar state (exp2 domain) ---
        float tm = -1e30f;
        #pragma unroll
        for (int i = 0; i < 16; ++i) { tm = fmaxf(tm, s0[i]); tm = fmaxf(tm, s1[i]); }
        tm = fmaxf(tm, __shfl_xor(tm, 32, 64));
        float nm = fmaxf(mrun, tm);
        float corr = exp2f(mrun - nm);
        mrun = nm;
        float p0[16], p1[16];
        float ps = 0.f;
        #pragma unroll
        for (int i = 0; i < 16; ++i) { p0[i] = exp2f(s0[i] - nm); ps += p0[i]; }
        #pragma unroll
        for (int i = 0; i < 16; ++i) { p1[i] = exp2f(s1[i] - nm); ps += p1[i]; }
        ps += __shfl_xor(ps, 32, 64);
        lrun = lrun * corr + ps;
        #pragma unroll
        for (int i = 0; i < 16; ++i) { o0[i] *= corr; o1[i] *= corr; }

        // pack P to f16 pairs: U[tile][g*2+w]
        u32 U0[8], U1[8];
        #pragma unroll
        for (int g = 0; g < 4; ++g) {
            U0[g * 2 + 0] = pkh(p0[4 * g + 0], p0[4 * g + 1]);
            U0[g * 2 + 1] = pkh(p0[4 * g + 2], p0[4 * g + 3]);
            U1[g * 2 + 0] = pkh(p1[4 * g + 0], p1[4 * g + 1]);
            U1[g * 2 + 1] = pkh(p1[4 * g + 2], p1[4 * g + 3]);
        }

        // --- PV: O^T accumulate, B-frags built by half-exchange ---
        #pragma unroll
        for (int c = 0; c < 4; ++c) {
            const u32* Us = (c < 2) ? U0 : U1;
            int gl = 2 * (c & 1);
            u32 x0 = Us[(gl + 1) * 2 + 0], x1 = Us[(gl + 1) * 2 + 1];
            u32 y0 = Us[gl * 2 + 0],       y1 = Us[gl * 2 + 1];
            u32 s0w = h ? y0 : x0;
            u32 s1w = h ? y1 : x1;
            u32 r0 = (u32)__shfl_xor((int)s0w, 32, 64);
            u32 r1 = (u32)__shfl_xor((int)s1w, 32, 64);
            u32 own0 = h ? x0 : y0, own1 = h ? x1 : y1;
            u32 w0 = h ? r0 : own0;
            u32 w1 = h ? r1 : own1;
            u32 w2 = h ? own0 : r0;
            u32 w3 = h ? own1 : r1;
            u32x4 fw = {w0, w1, w2, w3};
            f16x8 pb = __builtin_bit_cast(f16x8, fw);
            int col = c * 32 + h * 16;
            int r0r = q, r1r = 32 + q;
            f16x8 va0 = *(const f16x8*)(vb + ((r0r * 128 + col) ^ ((r0r & 7) << 4)));
            f16x8 va1 = *(const f16x8*)(vb + ((r1r * 128 + col) ^ ((r1r & 7) << 4)));
            o0 = __builtin_amdgcn_mfma_f32_32x32x16_f16(va0, pb, o0, 0, 0, 0);
            o1 = __builtin_amdgcn_mfma_f32_32x32x16_f16(va1, pb, o1, 0, 0, 0);
        }
        __syncthreads();
    }

    // ---- epilogue: O^T -> LDS transpose -> f16 partial, ml ----
    float invl = 1.f / lrun;
    char* ob = smem;
    int row = wv * 32 + q;
    #pragma unroll
    for (int g = 0; g < 4; ++g) {
        #pragma unroll
        for (int w = 0; w < 2; ++w) {
            u32 u0 = pkh(o0[4 * g + 2 * w] * invl, o0[4 * g + 2 * w + 1] * invl);
            u32 u1 = pkh(o1[4 * g + 2 * w] * invl, o1[4 * g + 2 * w + 1] * invl);
            int col0 = 16 * g + 8 * h + 4 * w;      // d*2 bytes, d = 8g+4h+2w
            *(u32*)(ob + ((row * 128 + col0) ^ ((row & 7) << 4))) = u0;
            *(u32*)(ob + ((row * 128 + col0 + 64) ^ ((row & 7) << 4))) = u1;
        }
    }
    if (h == 0) {
        float2 mlv = {mrun, lrun};
        ((float2*)partML)[((size_t)z * BH + bh) * Nc + qt * 64 + row] = mlv;
    }
    __syncthreads();
    {
        int r = tid >> 1, half = tid & 1;
        char* dst = partO + (((size_t)z * BH + bh) * Nc + qt * 64 + r) * 128 + half * 64;
        #pragma unroll
        for (int j = 0; j < 4; ++j) {
            float4 val = *(float4*)(ob + ((r * 128 + half * 64 + j * 16) ^ ((r & 7) << 4)));
            ((float4*)dst)[j] = val;
        }
    }
}

// ---------------- combine partials + inverse transform ----------------
__global__ void prope_combine_kernel(const char* __restrict__ wsb,
                                     const float* __restrict__ viewmats, const float* __restrict__ Ks,
                                     float* __restrict__ out) {
    int id = blockIdx.x * 256 + threadIdx.x;
    int seg = id & 3, rid = id >> 2;    // rid < BH*Nc
    int n = rid % Nc, bh = rid / Nc, b = bh >> 4;
    const float2* ml = (const float2*)(wsb + ML_OFF);
    float m[KS], l[KS];
    float mstar = -1e30f;
    #pragma unroll
    for (int s = 0; s < KS; ++s) {
        float2 v = ml[((size_t)s * BH + bh) * Nc + n];
        m[s] = v.x; l[s] = v.y;
        mstar = fmaxf(mstar, m[s]);
    }
    float wsum = 0.f, wgt[KS];
    #pragma unroll
    for (int s = 0; s < KS; ++s) { wgt[s] = exp2f(m[s] - mstar) * l[s]; wsum += wgt[s]; }
    float inv = 1.f / wsum;
    float acc[16];
    #pragma unroll
    for (int i = 0; i < 16; ++i) acc[i] = 0.f;
    #pragma unroll
    for (int s = 0; s < KS; ++s) {
        const char* op = wsb + PART_OFF + (((size_t)s * BH + bh) * Nc + n) * 128 + seg * 32;
        f16x8 a0 = *(const f16x8*)op;
        f16x8 a1 = *(const f16x8*)(op + 16);
        #pragma unroll
        for (int i = 0; i < 8; ++i) acc[i] += wgt[s] * (float)a0[i];
        #pragma unroll
        for (int i = 0; i < 8; ++i) acc[8 + i] += wgt[s] * (float)a1[i];
    }
    #pragma unroll
    for (int i = 0; i < 16; ++i) acc[i] *= inv;
    xf_seg<true>(acc, seg, n, b, 0, viewmats, Ks);
    float* go = out + ((size_t)bh * Nc + n) * 64 + seg * 16;
    #pragma unroll
    for (int i = 0; i < 4; ++i) ((float4*)go)[i] = ((const float4*)acc)[i];
}

extern "C" void kernel_launch(void* const* d_in, const int* in_sizes, int n_in,
                              void* d_out, int out_size, void* d_ws, size_t ws_size,
                              hipStream_t stream) {
    const float* q        = (const float*)d_in[0];
    const float* k        = (const float*)d_in[1];
    const float* v        = (const float*)d_in[2];
    const float* viewmats = (const float*)d_in[3];
    const float* Ks       = (const float*)d_in[4];
    char* wsb  = (char*)d_ws;
    float* out = (float*)d_out;

    prope_xform_kernel<<<1088 + 544, 256, 0, stream>>>(q, k, v, viewmats, Ks, wsb);
    prope_attn_mfma_kernel<<<dim3(NKT, BH, KS), 128, 0, stream>>>(wsb, wsb + PART_OFF,
                                                                  (float*)(wsb + ML_OFF));
    prope_combine_kernel<<<(BH * Nc * 4) / 256, 256, 0, stream>>>(wsb, viewmats, Ks, out);
}

// Round 5
// 48.027 us; speedup vs baseline: 15.2777x; 1.1427x over previous
//
#include <hip/hip_runtime.h>
#include <math.h>

typedef _Float16 f16;
typedef _Float16 f16x8 __attribute__((ext_vector_type(8)));
typedef __fp16 h16x2 __attribute__((ext_vector_type(2)));
typedef float f32x16 __attribute__((ext_vector_type(16)));
typedef unsigned int u32;
typedef u32 u32x4 __attribute__((ext_vector_type(4)));

constexpr int Bc = 2, Hc = 16, Cc = 4, PXc = 16, PYc = 16, EXTRAc = 64, HDc = 64;
constexpr int Nc = Cc * PXc * PYc + EXTRAc;   // 1088
constexpr int BH = Bc * Hc;                   // 32
constexpr int KT = 64;                        // keys per tile
constexpr int NKT = Nc / KT;                  // 17
constexpr int KS = 4;                         // key splits
constexpr int NQT = Nc / 32;                  // 34 q-tiles of 32 rows

// ws layout (bytes). All Q/K/V stored FRAGMENT-PACKED per bh (Nc*128 bytes each).
constexpr size_t TENS_SZ  = (size_t)BH * Nc * HDc * 2;       // 4,456,448
constexpr size_t PBH      = (size_t)Nc * 128;                // 139,264 per bh
constexpr size_t QF_OFF   = 0;
constexpr size_t KF_OFF   = QF_OFF + TENS_SZ;
constexpr size_t VT_OFF   = KF_OFF + TENS_SZ;
constexpr size_t PART_OFF = VT_OFF + TENS_SZ;                // KS * TENS_SZ f16 partials
constexpr size_t ML_OFF   = PART_OFF + (size_t)KS * TENS_SZ; // KS*BH*Nc float2

__device__ const float FREQS[8] = {1.0f, 0.5623413252f, 0.31622776601f, 0.17782794100f,
                                   0.1f, 0.05623413252f, 0.031622776602f, 0.017782794100f};
constexpr float QSCALE = 0.125f * 1.4426950408889634f;   // 1/sqrt(64) * log2(e)

// ---- inline camera matrices ----
__device__ __forceinline__ void compute_M(float* M, const float* __restrict__ vm,
                                          const float* __restrict__ Ks3, int b, int cam, int which) {
    const float* V  = vm + (b * Cc + cam) * 16;
    const float* K3 = Ks3 + (b * Cc + cam) * 9;
    float fx = K3[0] * (1.0f / 256.0f);
    float fy = K3[4] * (1.0f / 256.0f);
    float cx = K3[2] * (1.0f / 256.0f) - 0.5f;
    float cy = K3[5] * (1.0f / 256.0f) - 0.5f;
    if (which == 2) {  // P_inv
        float IV[16];
        IV[0] = V[0]; IV[1] = V[4]; IV[2] = V[8];
        IV[4] = V[1]; IV[5] = V[5]; IV[6] = V[9];
        IV[8] = V[2]; IV[9] = V[6]; IV[10] = V[10];
        float tx = V[3], ty = V[7], tz = V[11];
        IV[3]  = -(IV[0] * tx + IV[1] * ty + IV[2] * tz);
        IV[7]  = -(IV[4] * tx + IV[5] * ty + IV[6] * tz);
        IV[11] = -(IV[8] * tx + IV[9] * ty + IV[10] * tz);
        IV[12] = 0.f; IV[13] = 0.f; IV[14] = 0.f; IV[15] = 1.f;
        float ifx = 1.f / fx, ify = 1.f / fy;
        float ncx = -cx * ifx, ncy = -cy * ify;
        #pragma unroll
        for (int i = 0; i < 4; ++i) {
            M[i * 4 + 0] = IV[i * 4 + 0] * ifx;
            M[i * 4 + 1] = IV[i * 4 + 1] * ify;
            M[i * 4 + 2] = IV[i * 4 + 0] * ncx + IV[i * 4 + 1] * ncy + IV[i * 4 + 2];
            M[i * 4 + 3] = IV[i * 4 + 3];
        }
    } else {
        float P[16];
        #pragma unroll
        for (int j = 0; j < 4; ++j) {
            P[0 * 4 + j] = fx * V[0 * 4 + j] + cx * V[2 * 4 + j];
            P[1 * 4 + j] = fy * V[1 * 4 + j] + cy * V[2 * 4 + j];
            P[2 * 4 + j] = V[2 * 4 + j];
            P[3 * 4 + j] = V[3 * 4 + j];
        }
        if (which == 0) {
            #pragma unroll
            for (int i = 0; i < 16; ++i) M[i] = P[i];
        } else {
            #pragma unroll
            for (int i = 0; i < 4; ++i)
                #pragma unroll
                for (int j = 0; j < 4; ++j) M[i * 4 + j] = P[j * 4 + i];
        }
    }
}

template <bool INV>
__device__ __forceinline__ void xf_seg(float* v16, int seg, int n, int b, int which,
                                       const float* __restrict__ vm, const float* __restrict__ Ks3) {
    if (n < EXTRAc) return;
    int sidx = n - EXTRAc;
    int cam = sidx >> 8;
    if (seg < 2) {
        float M[16];
        compute_M(M, vm, Ks3, b, cam, which);
        #pragma unroll
        for (int g = 0; g < 4; ++g) {
            float a0 = v16[4 * g], a1 = v16[4 * g + 1], a2 = v16[4 * g + 2], a3 = v16[4 * g + 3];
            v16[4 * g + 0] = M[0]  * a0 + M[1]  * a1 + M[2]  * a2 + M[3]  * a3;
            v16[4 * g + 1] = M[4]  * a0 + M[5]  * a1 + M[6]  * a2 + M[7]  * a3;
            v16[4 * g + 2] = M[8]  * a0 + M[9]  * a1 + M[10] * a2 + M[11] * a3;
            v16[4 * g + 3] = M[12] * a0 + M[13] * a1 + M[14] * a2 + M[15] * a3;
        }
    } else {
        float pos = (seg == 2) ? (float)(sidx & (PXc - 1)) : (float)((sidx >> 4) & (PYc - 1));
        #pragma unroll
        for (int f = 0; f < 8; ++f) {
            float s, c;
            __sincosf(pos * FREQS[f], &s, &c);
            float xa = v16[f], xb = v16[8 + f];
            if (INV) {
                v16[f]     = c * xa - s * xb;
                v16[8 + f] = s * xa + c * xb;
            } else {
                v16[f]     = c * xa + s * xb;
                v16[8 + f] = -s * xa + c * xb;
            }
        }
    }
}

__device__ __forceinline__ u32 pkh(float a, float b) {
    h16x2 r = __builtin_amdgcn_cvt_pkrtz(a, b);
    return __builtin_bit_cast(u32, r);
}

__device__ __forceinline__ f32x16 zero16() {
    f32x16 z = {0.f,0.f,0.f,0.f,0.f,0.f,0.f,0.f,0.f,0.f,0.f,0.f,0.f,0.f,0.f,0.f};
    return z;
}

// ---------------- xform: Q,K,V -> fragment-packed f16 ----------------
// Q chunk (qt,c,h,q):   qbase + qt*4096 + (c*2+h)*512 + q*16
// K chunk (kt,c,rh,h,q): kbase + kt*8192 + ((c*2+rh)*2+h)*512 + q*16
// V chunk (kt,c,dh,h,dq): vbase + kt*8192 + ((c*2+dh)*2+h)*512 + dq*16
__global__ void prope_xform_kernel(const float* __restrict__ q, const float* __restrict__ k,
                                   const float* __restrict__ v,
                                   const float* __restrict__ viewmats, const float* __restrict__ Ks,
                                   char* __restrict__ wsb) {
    __shared__ f16 tile[64][72];
    if (blockIdx.x < 1088) {   // ---- Q/K path ----
        int id = blockIdx.x * 256 + threadIdx.x;
        int seg = id & 3;                  // = c
        int rid = id >> 2;
        int tensor = rid / (BH * Nc);      // 0=Q, 1=K
        int row = rid - tensor * (BH * Nc);
        int n = row % Nc;
        int bhq = row / Nc;
        int b = bhq >> 4;
        const float* src = (tensor ? k : q) + (size_t)row * 64 + seg * 16;
        float vals[16];
        #pragma unroll
        for (int i = 0; i < 4; ++i) ((float4*)vals)[i] = ((const float4*)src)[i];
        xf_seg<false>(vals, seg, n, b, tensor ? 2 : 1, viewmats, Ks);
        float scale = tensor ? 1.0f : QSCALE;
        f16 o[16];
        #pragma unroll
        for (int i = 0; i < 16; ++i) o[i] = (f16)(vals[i] * scale);
        if (tensor == 0) {
            char* base = wsb + QF_OFF + (size_t)bhq * PBH + (size_t)(n >> 5) * 4096;
            int qq = n & 31;
            *(float4*)(base + (seg * 2 + 0) * 512 + qq * 16) = ((float4*)o)[0];
            *(float4*)(base + (seg * 2 + 1) * 512 + qq * 16) = ((float4*)o)[1];
        } else {
            char* base = wsb + KF_OFF + (size_t)bhq * PBH + (size_t)(n >> 6) * 8192;
            int kk = n & 63, rh = kk >> 5, qq = kk & 31;
            *(float4*)(base + (((seg * 2 + rh) * 2 + 0) * 32 + qq) * 16) = ((float4*)o)[0];
            *(float4*)(base + (((seg * 2 + rh) * 2 + 1) * 32 + qq) * 16) = ((float4*)o)[1];
        }
    } else {                   // ---- V path: transpose + fragment-pack ----
        int vb = blockIdx.x - 1088;
        int kt = vb >> 5, bh = vb & 31;
        int b = bh >> 4;
        int t = threadIdx.x;
        {
            int r = t >> 2, seg = t & 3;
            int n = kt * 64 + r;
            const float* src = v + ((size_t)bh * Nc + n) * 64 + seg * 16;
            float vals[16];
            #pragma unroll
            for (int i = 0; i < 4; ++i) ((float4*)vals)[i] = ((const float4*)src)[i];
            xf_seg<false>(vals, seg, n, b, 2, viewmats, Ks);
            #pragma unroll
            for (int i = 0; i < 16; ++i) tile[r][seg * 16 + i] = (f16)vals[i];
        }
        __syncthreads();
        {
            int d = t >> 2, ks = t & 3;    // ks = c
            f16 o[16];
            #pragma unroll
            for (int j = 0; j < 16; ++j) o[j] = tile[ks * 16 + j][d];
            int dh = d >> 5, dq = d & 31;
            char* base = wsb + VT_OFF + (size_t)bh * PBH + (size_t)kt * 8192;
            *(float4*)(base + (((ks * 2 + dh) * 2 + 0) * 32 + dq) * 16) = ((float4*)o)[0];
            *(float4*)(base + (((ks * 2 + dh) * 2 + 1) * 32 + dq) * 16) = ((float4*)o)[1];
        }
    }
}

// ---------------- MFMA flash attention: 1 wave/block, no staging ----------------
__global__ __launch_bounds__(64, 3) void prope_attn_mfma_kernel(
    const char* __restrict__ wsb, char* __restrict__ partO, float* __restrict__ partML) {
    __shared__ char ob[4096];   // epilogue transpose only

    const int lane = threadIdx.x;
    const int q = lane & 31, h = lane >> 5;
    const int qt = blockIdx.x, bh = blockIdx.y, z = blockIdx.z;
    const int ts = (NKT * z) / KS, te = (NKT * (z + 1)) / KS;

    const char* kfb = wsb + KF_OFF + (size_t)bh * PBH;
    const char* vfb = wsb + VT_OFF + (size_t)bh * PBH;
    const char* qfb = wsb + QF_OFF + (size_t)bh * PBH + (size_t)qt * 4096;

    // Q B-fragments (coalesced: lane*16)
    f16x8 qb[4];
    #pragma unroll
    for (int c = 0; c < 4; ++c) qb[c] = *(const f16x8*)(qfb + c * 1024 + lane * 16);

    f32x16 o0 = zero16(), o1 = zero16();
    float mrun = -1e30f, lrun = 0.f;

    for (int it = ts; it < te; ++it) {
        const char* kb = kfb + (size_t)it * 8192;
        const char* vb = vfb + (size_t)it * 8192;

        // K A-fragments straight from L2 (each load: 64 lanes x 16B contiguous)
        f16x8 ka0[4], ka1[4];
        #pragma unroll
        for (int c = 0; c < 4; ++c) {
            ka0[c] = *(const f16x8*)(kb + (c * 2 + 0) * 1024 + lane * 16);
            ka1[c] = *(const f16x8*)(kb + (c * 2 + 1) * 1024 + lane * 16);
        }

        // --- S^T = K . Q : rows=keys, cols=q ---
        f32x16 s0 = zero16(), s1 = zero16();
        #pragma unroll
        for (int c = 0; c < 4; ++c) {
            s0 = __builtin_amdgcn_mfma_f32_32x32x16_f16(ka0[c], qb[c], s0, 0, 0, 0);
            s1 = __builtin_amdgcn_mfma_f32_32x32x16_f16(ka1[c], qb[c], s1, 0, 0, 0);
        }

        // V A-fragments issued now; latency hidden under softmax
        f16x8 va0[4], va1[4];
        #pragma unroll
        for (int c = 0; c < 4; ++c) {
            va0[c] = *(const f16x8*)(vb + (c * 2 + 0) * 1024 + lane * 16);
            va1[c] = *(const f16x8*)(vb + (c * 2 + 1) * 1024 + lane * 16);
        }

        // --- online softmax: per-lane scalar state (exp2 domain) ---
        float tm = -1e30f;
        #pragma unroll
        for (int i = 0; i < 16; ++i) { tm = fmaxf(tm, s0[i]); tm = fmaxf(tm, s1[i]); }
        tm = fmaxf(tm, __shfl_xor(tm, 32, 64));
        float nm = fmaxf(mrun, tm);
        float corr = exp2f(mrun - nm);
        mrun = nm;
        float p0[16], p1[16];
        float ps = 0.f;
        #pragma unroll
        for (int i = 0; i < 16; ++i) { p0[i] = exp2f(s0[i] - nm); ps += p0[i]; }
        #pragma unroll
        for (int i = 0; i < 16; ++i) { p1[i] = exp2f(s1[i] - nm); ps += p1[i]; }
        ps += __shfl_xor(ps, 32, 64);
        lrun = lrun * corr + ps;
        #pragma unroll
        for (int i = 0; i < 16; ++i) { o0[i] *= corr; o1[i] *= corr; }

        // pack P to f16 pairs
        u32 U0[8], U1[8];
        #pragma unroll
        for (int g = 0; g < 4; ++g) {
            U0[g * 2 + 0] = pkh(p0[4 * g + 0], p0[4 * g + 1]);
            U0[g * 2 + 1] = pkh(p0[4 * g + 2], p0[4 * g + 3]);
            U1[g * 2 + 0] = pkh(p1[4 * g + 0], p1[4 * g + 1]);
            U1[g * 2 + 1] = pkh(p1[4 * g + 2], p1[4 * g + 3]);
        }

        // --- PV: O^T accumulate, B-frags by half-exchange ---
        #pragma unroll
        for (int c = 0; c < 4; ++c) {
            const u32* Us = (c < 2) ? U0 : U1;
            int gl = 2 * (c & 1);
            u32 x0 = Us[(gl + 1) * 2 + 0], x1 = Us[(gl + 1) * 2 + 1];
            u32 y0 = Us[gl * 2 + 0],       y1 = Us[gl * 2 + 1];
            u32 s0w = h ? y0 : x0;
            u32 s1w = h ? y1 : x1;
            u32 r0 = (u32)__shfl_xor((int)s0w, 32, 64);
            u32 r1 = (u32)__shfl_xor((int)s1w, 32, 64);
            u32 own0 = h ? x0 : y0, own1 = h ? x1 : y1;
            u32 w0 = h ? r0 : own0;
            u32 w1 = h ? r1 : own1;
            u32 w2 = h ? own0 : r0;
            u32 w3 = h ? own1 : r1;
            u32x4 fw = {w0, w1, w2, w3};
            f16x8 pb = __builtin_bit_cast(f16x8, fw);
            o0 = __builtin_amdgcn_mfma_f32_32x32x16_f16(va0[c], pb, o0, 0, 0, 0);
            o1 = __builtin_amdgcn_mfma_f32_32x32x16_f16(va1[c], pb, o1, 0, 0, 0);
        }
    }

    // ---- epilogue: O^T -> LDS transpose -> f16 partial, ml ----
    float invl = 1.f / lrun;
    #pragma unroll
    for (int g = 0; g < 4; ++g) {
        #pragma unroll
        for (int w = 0; w < 2; ++w) {
            u32 u0 = pkh(o0[4 * g + 2 * w] * invl, o0[4 * g + 2 * w + 1] * invl);
            u32 u1 = pkh(o1[4 * g + 2 * w] * invl, o1[4 * g + 2 * w + 1] * invl);
            int col0 = 16 * g + 8 * h + 4 * w;      // d*2 bytes, d = 8g+4h+2w
            *(u32*)(ob + ((q * 128 + col0) ^ ((q & 7) << 4))) = u0;
            *(u32*)(ob + ((q * 128 + col0 + 64) ^ ((q & 7) << 4))) = u1;
        }
    }
    if (h == 0) {
        float2 mlv = {mrun, lrun};
        ((float2*)partML)[((size_t)z * BH + bh) * Nc + qt * 32 + q] = mlv;
    }
    __syncthreads();
    {
        int r = lane >> 1, half = lane & 1;
        char* dst = partO + (((size_t)z * BH + bh) * Nc + qt * 32 + r) * 128 + half * 64;
        #pragma unroll
        for (int j = 0; j < 4; ++j) {
            float4 val = *(float4*)(ob + ((r * 128 + half * 64 + j * 16) ^ ((r & 7) << 4)));
            ((float4*)dst)[j] = val;
        }
    }
}

// ---------------- combine partials + inverse transform ----------------
__global__ void prope_combine_kernel(const char* __restrict__ wsb,
                                     const float* __restrict__ viewmats, const float* __restrict__ Ks,
                                     float* __restrict__ out) {
    int id = blockIdx.x * 256 + threadIdx.x;
    int seg = id & 3, rid = id >> 2;    // rid < BH*Nc
    int n = rid % Nc, bh = rid / Nc, b = bh >> 4;
    const float2* ml = (const float2*)(wsb + ML_OFF);
    float m[KS], l[KS];
    float mstar = -1e30f;
    #pragma unroll
    for (int s = 0; s < KS; ++s) {
        float2 v = ml[((size_t)s * BH + bh) * Nc + n];
        m[s] = v.x; l[s] = v.y;
        mstar = fmaxf(mstar, m[s]);
    }
    float wsum = 0.f, wgt[KS];
    #pragma unroll
    for (int s = 0; s < KS; ++s) { wgt[s] = exp2f(m[s] - mstar) * l[s]; wsum += wgt[s]; }
    float inv = 1.f / wsum;
    float acc[16];
    #pragma unroll
    for (int i = 0; i < 16; ++i) acc[i] = 0.f;
    #pragma unroll
    for (int s = 0; s < KS; ++s) {
        const char* op = wsb + PART_OFF + (((size_t)s * BH + bh) * Nc + n) * 128 + seg * 32;
        f16x8 a0 = *(const f16x8*)op;
        f16x8 a1 = *(const f16x8*)(op + 16);
        #pragma unroll
        for (int i = 0; i < 8; ++i) acc[i] += wgt[s] * (float)a0[i];
        #pragma unroll
        for (int i = 0; i < 8; ++i) acc[8 + i] += wgt[s] * (float)a1[i];
    }
    #pragma unroll
    for (int i = 0; i < 16; ++i) acc[i] *= inv;
    xf_seg<true>(acc, seg, n, b, 0, viewmats, Ks);
    float* go = out + ((size_t)bh * Nc + n) * 64 + seg * 16;
    #pragma unroll
    for (int i = 0; i < 4; ++i) ((float4*)go)[i] = ((const float4*)acc)[i];
}

extern "C" void kernel_launch(void* const* d_in, const int* in_sizes, int n_in,
                              void* d_out, int out_size, void* d_ws, size_t ws_size,
                              hipStream_t stream) {
    const float* q        = (const float*)d_in[0];
    const float* k        = (const float*)d_in[1];
    const float* v        = (const float*)d_in[2];
    const float* viewmats = (const float*)d_in[3];
    const float* Ks       = (const float*)d_in[4];
    char* wsb  = (char*)d_ws;
    float* out = (float*)d_out;

    prope_xform_kernel<<<1088 + 544, 256, 0, stream>>>(q, k, v, viewmats, Ks, wsb);
    prope_attn_mfma_kernel<<<dim3(NQT, BH, KS), 64, 0, stream>>>(wsb, wsb + PART_OFF,
                                                                 (float*)(wsb + ML_OFF));
    prope_combine_kernel<<<(BH * Nc * 4) / 256, 256, 0, stream>>>(wsb, viewmats, Ks, out);
}